// Round 4
// baseline (488.738 us; speedup 1.0000x reference)
//
#include <hip/hip_runtime.h>

// CostVolume1D: out[n,i,h,w] = (1/C) * sum_c f1[n,c,h,w] * f2pad[n,c,h,w+i-4]
// N=4, C=128, H=192, W=640, D=4 -> 9 shifts.
//
// Memory-bound floor: 503 MB read + 17.7 MB write => ~83 us @6.3 TB/s.
// Round-1 measured 158 us with VGPR_Count=64: the occupancy-driven register
// allocator destroyed the software pipeline (needed ~160 live regs, got 64
// -> near-immediate vmcnt waits, full HBM latency exposed per load batch,
// only ~1.9 waves/SIMD to hide it). Fix:
//   * __launch_bounds__(160, 1): permit up to 256 VGPRs. ~200 VGPRs still
//     allows 8 waves/CU = exactly our 3 blocks x 2.5 waves residency.
//   * Explicit two-phase double buffer (A/B register sets, body written
//     twice, 4 channels per phase): no rotating copies; 16 float4 loads
//     (16 KB/wave) stay in flight across a full 144-FMA compute phase.
//
// LDS-free halo: each thread owns an aligned float4 of outputs (w..w+3),
// loads f2[w-4..w+7] as 3 aligned float4s; overlap is L1-absorbed.
// Row-edge zero padding: clamp halo address in-bounds, zero the affected
// outputs (channel-invariant OOB property) at store time.
// (Rounds 2-3 were container/infra failures; design unchanged, macros
//  rewritten as inline functions as a compiler-pathology hedge.)

constexpr int DD = 4;
constexpr int NS = 2 * DD + 1;          // 9
constexpr int N_ = 4, C_ = 128, H_ = 192, W_ = 640;
constexpr int HW = H_ * W_;             // 122880

__device__ __forceinline__ float4 ld4(const float* p) {
    return *reinterpret_cast<const float4*>(p);
}

// Issue 16 float4 loads for channels cbase..cbase+3 into one phase buffer.
__device__ __forceinline__ void loadp(const float* __restrict__ pa,
                                      const float* __restrict__ pv,
                                      int off0, int off2, int cbase,
                                      float4 (&Aa)[4], float4 (&Uu)[4],
                                      float4 (&Vv)[4], float4 (&Xx)[4])
{
#pragma unroll
    for (int k = 0; k < 4; ++k) {
        const float* qa = pa + (size_t)(cbase + k) * HW;
        const float* q1 = pv + (size_t)(cbase + k) * HW;
        Aa[k] = ld4(qa);
        Uu[k] = ld4(q1 + off0);
        Vv[k] = ld4(q1);
        Xx[k] = ld4(q1 + off2);
    }
}

// 144 FMAs on one phase buffer. vv[m] = f2row[w - 4 + m], m = 0..11.
__device__ __forceinline__ void comp(const float4 (&Aa)[4], const float4 (&Uu)[4],
                                     const float4 (&Vv)[4], const float4 (&Xx)[4],
                                     float (&acc)[NS][4])
{
#pragma unroll
    for (int k = 0; k < 4; ++k) {
        float vv[12];
        *(float4*)&vv[0] = Uu[k];
        *(float4*)&vv[4] = Vv[k];
        *(float4*)&vv[8] = Xx[k];
        const float* ap = (const float*)&Aa[k];
#pragma unroll
        for (int i = 0; i < NS; ++i) {
#pragma unroll
            for (int j = 0; j < 4; ++j)
                acc[i][j] = fmaf(ap[j], vv[i + j], acc[i][j]);
        }
    }
}

__global__ __launch_bounds__(160, 1)
void cost_volume_kernel(const float* __restrict__ f1,
                        const float* __restrict__ f2,
                        float* __restrict__ out)
{
    const int t   = threadIdx.x;        // 0..159, owns w = 4t..4t+3
    const int row = blockIdx.x;         // n*H + h
    const int n   = row / H_;
    const int h   = row - n * H_;
    const int w   = 4 * t;

    const size_t base = (size_t)n * C_ * HW + (size_t)h * W_ + w;
    const float* pa = f1 + base;
    const float* pv = f2 + base;
    const int off0 = (w >= 4)     ? -4 : 0;   // left halo clamp (t==0)
    const int off2 = (w + 7 < W_) ?  4 : 0;   // right halo clamp (t==159)

    float acc[NS][4];
#pragma unroll
    for (int i = 0; i < NS; ++i)
#pragma unroll
        for (int j = 0; j < 4; ++j) acc[i][j] = 0.f;

    // Two phase buffers, 4 channels each: 8 arrays x 4 float4 = 128 VGPRs.
    float4 A[4], U[4], V[4], X[4];
    float4 B[4], R[4], S[4], T[4];

    loadp(pa, pv, off0, off2, 0, A, U, V, X);          // channels 0..3
    for (int c = 0; c < C_ - 8; c += 8) {              // c = 0, 8, ..., 112
        loadp(pa, pv, off0, off2, c + 4, B, R, S, T);  // prefetch next phase
        comp(A, U, V, X, acc);                         // compute ch c..c+3
        loadp(pa, pv, off0, off2, c + 8, A, U, V, X);  // prefetch phase after
        comp(B, R, S, T, acc);                         // compute ch c+4..c+7
    }
    loadp(pa, pv, off0, off2, C_ - 4, B, R, S, T);     // channels 124..127
    comp(A, U, V, X, acc);                             // channels 120..123
    comp(B, R, S, T, acc);                             // channels 124..127

    constexpr float scale = 1.0f / (float)C_;
    float* op = out + (size_t)n * NS * HW + (size_t)h * W_ + w;
#pragma unroll
    for (int i = 0; i < NS; ++i) {
        float4 o;
        float* oo = (float*)&o;
#pragma unroll
        for (int j = 0; j < 4; ++j) {
            const int idx = w + i + j - DD;   // f2 column this product used
            oo[j] = (idx >= 0 && idx < W_) ? acc[i][j] * scale : 0.f;
        }
        *reinterpret_cast<float4*>(op + (size_t)i * HW) = o;
    }
}

extern "C" void kernel_launch(void* const* d_in, const int* in_sizes, int n_in,
                              void* d_out, int out_size, void* d_ws, size_t ws_size,
                              hipStream_t stream) {
    const float* f1 = (const float*)d_in[0];
    const float* f2 = (const float*)d_in[1];
    float* out = (float*)d_out;
    dim3 grid(N_ * H_);   // 768 blocks = one per (n,h) row; exactly 3/CU
    dim3 block(160);      // one row of 640 floats = 160 lanes x float4
    cost_volume_kernel<<<grid, block, 0, stream>>>(f1, f2, out);
}